// Round 1
// baseline (535.650 us; speedup 1.0000x reference)
//
#include <hip/hip_runtime.h>

// Problem constants
namespace {
constexpr int kNC = 128;   // in channels per group
constexpr int kNZ = 256;   // out channels per group
constexpr int kG  = 64;    // groups (HP*WP)
constexpr int kK  = 2048;  // kNC * 4 * 4
constexpr int kM  = 512;   // B(32) * 16 positions
constexpr int TM  = 32;    // z tile
constexpr int TN  = 128;   // m tile
constexpr int KB  = 16;    // k chunk = one nc's 4x4 kernel
constexpr float kLrelu = 0.2f;
constexpr float kEps   = 1e-5f;
}  // namespace

// Pass 1: grouped conv as tiled GEMM + per-channel sum/sumsq.
// Writes raw conv output directly into d_out in FOLD layout:
//   out[b][z][hp*4+oy][wp*4+ox]
__global__ __launch_bounds__(256) void conv_stats(
    const float* __restrict__ input,   // [32,128,64,64]
    const float* __restrict__ weight,  // [16384, 2048] (nc,ky,kx contiguous)
    float* __restrict__ out,           // [32,256,32,32]
    float* __restrict__ stats)         // [16384][2] (sum, sumsq)
{
  const int g  = blockIdx.z;           // group = hp*8+wp
  const int hp = g >> 3, wp = g & 7;
  const int z0 = blockIdx.x * TM;      // z tile base
  const int m0 = blockIdx.y * TN;      // m tile base (m = b*16 + oy*4 + ox)
  const int tid = threadIdx.x;
  const int tx = tid & 31, ty = tid >> 5;

  __shared__ float As[KB][TM + 4];     // +4 pad: 16B-aligned rows, no write conflicts
  __shared__ float Bs[KB][TN + 4];

  float acc[4][4] = {};

  // A-load mapping: thread -> (k row ar, z col az and az+16); coalesced along k
  const int ar = tid & 15;
  const int az = tid >> 4;
  // B-gather mapping: thread -> (k row br, 8 consecutive m at bc0)
  const int br  = tid & 15;
  const int bc0 = (tid >> 4) << 3;
  const int mb  = (m0 + bc0) >> 4;     // batch index (fixed for the 8 cols)
  const int p0  = bc0 & 15;            // base position (0 or 8)
  const int ky  = br >> 2, kx = br & 3;

  const float* wbase = weight + (size_t)(g * kNZ + z0) * kK + ar;
  const float* ibase = input + (((size_t)mb * kNC) * 64 + hp * 8) * 64 + wp * 8;

  for (int k0 = 0; k0 < kK; k0 += KB) {
    // --- gather B chunk into regs (im2col: stride 2, pad 1, 8x8 patch) ---
    const int nc = k0 >> 4;            // chunk == exactly one nc
    const float* irow = ibase + (size_t)nc * 4096;  // 64*64
    float bv[8];
#pragma unroll
    for (int cc = 0; cc < 8; ++cc) {
      int pos = p0 + cc;
      int oy = pos >> 2, ox = pos & 3;
      int iy = 2 * oy - 1 + ky;
      int ix = 2 * ox - 1 + kx;
      bool okf = ((unsigned)iy < 8u) && ((unsigned)ix < 8u);
      bv[cc] = okf ? irow[iy * 64 + ix] : 0.f;
    }
    // --- load A chunk (weights): contiguous along k ---
    float a0 = wbase[(size_t)az * kK + k0];
    float a1 = wbase[(size_t)(az + 16) * kK + k0];

    __syncthreads();  // previous chunk's reads done
    As[ar][az]      = a0;
    As[ar][az + 16] = a1;
    *(float4*)&Bs[br][bc0]     = make_float4(bv[0], bv[1], bv[2], bv[3]);
    *(float4*)&Bs[br][bc0 + 4] = make_float4(bv[4], bv[5], bv[6], bv[7]);
    __syncthreads();

#pragma unroll
    for (int kk = 0; kk < KB; ++kk) {
      float4 av = *(const float4*)&As[kk][ty * 4];
      float4 bw = *(const float4*)&Bs[kk][tx * 4];
      float a[4] = {av.x, av.y, av.z, av.w};
      float b[4] = {bw.x, bw.y, bw.z, bw.w};
#pragma unroll
      for (int i = 0; i < 4; ++i)
#pragma unroll
        for (int j = 0; j < 4; ++j)
          acc[i][j] = fmaf(a[i], b[j], acc[i][j]);
    }
  }

  // --- per-channel stats: reduce across the 32 tx lanes (half-wave) ---
#pragma unroll
  for (int i = 0; i < 4; ++i) {
    float s  = acc[i][0] + acc[i][1] + acc[i][2] + acc[i][3];
    float ss = fmaf(acc[i][0], acc[i][0],
               fmaf(acc[i][1], acc[i][1],
               fmaf(acc[i][2], acc[i][2], acc[i][3] * acc[i][3])));
#pragma unroll
    for (int off = 1; off < 32; off <<= 1) {
      s  += __shfl_xor(s, off);
      ss += __shfl_xor(ss, off);
    }
    if (tx == 0) {
      int ch = g * kNZ + z0 + ty * 4 + i;
      atomicAdd(&stats[2 * ch],     s);
      atomicAdd(&stats[2 * ch + 1], ss);
    }
  }

  // --- write raw conv result to d_out in fold layout ---
  {
    const int m = m0 + tx * 4;         // 4 consecutive m => ox = 0..3, same oy
    const int b = m >> 4;
    const int oy = (m & 15) >> 2;
    float* obase = out + (((size_t)b * kNZ + z0 + ty * 4) * 32 + hp * 4 + oy) * 32 + wp * 4;
#pragma unroll
    for (int i = 0; i < 4; ++i) {
      *(float4*)(obase + (size_t)i * 1024) =
          make_float4(acc[i][0], acc[i][1], acc[i][2], acc[i][3]);
    }
  }
}

// Pass 2: in-place BatchNorm (batch stats) + LeakyReLU on the fold-layout buffer.
__global__ __launch_bounds__(256) void bn_lrelu(
    float* __restrict__ out,
    const float* __restrict__ stats,
    const float* __restrict__ gamma,
    const float* __restrict__ beta)
{
  size_t t = (size_t)blockIdx.x * blockDim.x + threadIdx.x;
  size_t o = t * 4;                    // float4 per thread
  int X0 = (int)(o & 31);
  int Y  = (int)((o >> 5) & 31);
  int z  = (int)((o >> 10) & 255);
  int ch = ((Y >> 2) * 8 + (X0 >> 2)) * kNZ + z;  // (hp*8+wp)*256 + z
  float s  = stats[2 * ch];
  float ss = stats[2 * ch + 1];
  float mean = s * (1.f / 512.f);
  float var  = fmaf(-mean, mean, ss * (1.f / 512.f));
  float inv  = gamma[ch] * rsqrtf(var + kEps);
  float sh   = fmaf(-mean, inv, beta[ch]);
  float4 v = *(float4*)&out[o];
  float vv[4] = {v.x, v.y, v.z, v.w};
#pragma unroll
  for (int j = 0; j < 4; ++j) {
    float y = fmaf(vv[j], inv, sh);
    vv[j] = y > 0.f ? y : kLrelu * y;
  }
  *(float4*)&out[o] = make_float4(vv[0], vv[1], vv[2], vv[3]);
}

extern "C" void kernel_launch(void* const* d_in, const int* in_sizes, int n_in,
                              void* d_out, int out_size, void* d_ws, size_t ws_size,
                              hipStream_t stream) {
  const float* input  = (const float*)d_in[0];
  const float* weight = (const float*)d_in[1];
  const float* gamma  = (const float*)d_in[2];
  const float* beta   = (const float*)d_in[3];
  float* out   = (float*)d_out;
  float* stats = (float*)d_ws;  // 16384 * 2 floats = 128 KB

  hipMemsetAsync(stats, 0, (size_t)kG * kNZ * 2 * sizeof(float), stream);

  dim3 grid(kNZ / TM, kM / TN, kG);   // 8 x 4 x 64 = 2048 blocks
  conv_stats<<<grid, 256, 0, stream>>>(input, weight, out, stats);

  int n4 = out_size / 4;              // 2,097,152 float4s
  bn_lrelu<<<(n4 + 255) / 256, 256, 0, stream>>>(out, stats, gamma, beta);
}

// Round 3
// 457.883 us; speedup vs baseline: 1.1698x; 1.1698x over previous
//
#include <hip/hip_runtime.h>
#include <hip/hip_bf16.h>

namespace {
constexpr float kLrelu = 0.2f;
constexpr float kEps   = 1e-5f;
}

typedef short bf16x8 __attribute__((ext_vector_type(8)));
typedef float f32x4  __attribute__((ext_vector_type(4)));

// round-to-nearest-even f32 -> bf16 (no NaN path needed: inputs are finite
// random normals and products thereof)
static __device__ __forceinline__ unsigned f2bf(float x) {
  unsigned u = __float_as_uint(x);
  return (u + 0x7FFFu + ((u >> 16) & 1u)) >> 16;
}
static __device__ __forceinline__ unsigned packbf(float a, float b) {
  return f2bf(a) | (f2bf(b) << 16);
}

// Grouped conv as 64 x [256x512x2048] GEMM in bf16 MFMA + per-channel stats.
// Writes raw conv output into d_out in FOLD layout: out[b][z][hp*4+oy][wp*4+ox].
__global__ __launch_bounds__(1024, 4) void conv_mfma(
    const float* __restrict__ input,   // [32,128,64,64]
    const float* __restrict__ weight,  // [16384, 2048]  (k = nc*16 + ky*4 + kx)
    float* __restrict__ out,           // [32,256,32,32]
    float* __restrict__ stats)         // [16384][2] (sum, sumsq)
{
  // LDS tiles, row = 64B (32 bf16 = BK), XOR-swizzled in 16B granules:
  // granule g' of row r stored at (g' ^ ((r>>1)&3)).
  __shared__ __align__(16) char As[64 * 64];    // 64 z-rows
  __shared__ __align__(16) char Bs[512 * 64];   // 512 m-rows

  const int bid  = blockIdx.x;
  const int orig = (bid & 7) * 32 + (bid >> 3); // XCD-chunked swizzle (256 % 8 == 0)
  const int g    = orig >> 2;                   // group
  const int zt   = orig & 3;                    // z tile
  const int hp   = g >> 3, wp = g & 7;
  const int z0   = zt * 64;

  const int tid  = threadIdx.x;
  const int lane = tid & 63;
  const int w    = tid >> 6;                    // wave 0..15, m-range = w*32
  const int llo  = lane & 15, lhi = lane >> 4;

  // ---------------- B gather precompute (thread -> (m, ncs)) ----------------
  const int m   = tid & 511;                    // m = b*16 + oy*4 + ox
  const int ncs = tid >> 9;                     // which of the 2 nc's per chunk
  const int b   = m >> 4;
  const int oy  = (m >> 2) & 3;
  const int ox  = m & 3;

  int      toffe[16];                           // clamped element offsets (nc = ncs)
  unsigned bmask[8];                            // per-pair bf16 validity masks
  {
    unsigned short vm[16];
#pragma unroll
    for (int ky = 0; ky < 4; ++ky) {
#pragma unroll
      for (int kx = 0; kx < 4; ++kx) {
        const int t  = ky * 4 + kx;
        const int iy = 2 * oy - 1 + ky;
        const int ix = 2 * ox - 1 + kx;
        const bool ok = ((unsigned)iy < 8u) && ((unsigned)ix < 8u);
        const int iyc = iy < 0 ? 0 : (iy > 7 ? 7 : iy);
        const int ixc = ix < 0 ? 0 : (ix > 7 ? 7 : ix);
        toffe[t] = (b * 128 + ncs) * 4096 + (hp * 8 + iyc) * 64 + (wp * 8 + ixc);
        vm[t] = ok ? (unsigned short)0xFFFFu : (unsigned short)0;
      }
    }
#pragma unroll
    for (int j = 0; j < 8; ++j)
      bmask[j] = (unsigned)vm[2 * j] | ((unsigned)vm[2 * j + 1] << 16);
  }
  const int swzB = (m >> 1) & 3;
  char* const bw0 = Bs + m * 64 + (((2 * ncs)     ^ swzB) << 4);
  char* const bw1 = Bs + m * 64 + (((2 * ncs + 1) ^ swzB) << 4);

  // ---------------- A staging precompute (thread -> (z row, k pair)) --------
  const int az  = tid >> 4;                     // 0..63
  const int sub = tid & 15;                     // k pair index (k = sub*2)
  const float* const wrow =
      weight + ((size_t)(g * 256 + z0 + az)) * 2048 + sub * 2;
  char* const asp =
      As + az * 64 + ((((sub >> 2)) ^ ((az >> 1) & 3)) << 4) + (sub & 3) * 4;

  // ---------------- fragment read pointers (fixed) --------------------------
  const char* afp[4];
#pragma unroll
  for (int zf = 0; zf < 4; ++zf) {
    const int ar = zf * 16 + llo;
    afp[zf] = As + ar * 64 + ((lhi ^ ((ar >> 1) & 3)) << 4);
  }
  const char* bfp[2];
#pragma unroll
  for (int mf = 0; mf < 2; ++mf) {
    const int mr = w * 32 + mf * 16 + llo;
    bfp[mf] = Bs + mr * 64 + ((lhi ^ ((mr >> 1) & 3)) << 4);
  }

  f32x4 acc[4][2] = {};

  // ---------------- K loop: 64 chunks of BK=32 (2 nc each) ------------------
  for (int ck = 0; ck < 64; ++ck) {
    // global loads first (overlap with previous chunk's MFMAs)
    const float2 wv = *(const float2*)(wrow + ck * 32);
    const float* pin = input + (size_t)(ck * 2) * 4096;  // nc advance (uniform)
    float f[16];
#pragma unroll
    for (int t = 0; t < 16; ++t) f[t] = pin[toffe[t]];

    const unsigned au = packbf(wv.x, wv.y);
    unsigned u[8];
#pragma unroll
    for (int j = 0; j < 8; ++j) u[j] = packbf(f[2 * j], f[2 * j + 1]) & bmask[j];

    __syncthreads();   // previous compute done reading LDS
    *(unsigned*)asp = au;
    uint4 q0; q0.x = u[0]; q0.y = u[1]; q0.z = u[2]; q0.w = u[3];
    uint4 q1; q1.x = u[4]; q1.y = u[5]; q1.z = u[6]; q1.w = u[7];
    *(uint4*)bw0 = q0;
    *(uint4*)bw1 = q1;
    __syncthreads();   // tiles visible

    const bf16x8 bf0 = *(const bf16x8*)bfp[0];
    const bf16x8 bf1 = *(const bf16x8*)bfp[1];
#pragma unroll
    for (int zf = 0; zf < 4; ++zf) {
      const bf16x8 af = *(const bf16x8*)afp[zf];
      acc[zf][0] = __builtin_amdgcn_mfma_f32_16x16x32_bf16(af, bf0, acc[zf][0], 0, 0, 0);
      acc[zf][1] = __builtin_amdgcn_mfma_f32_16x16x32_bf16(af, bf1, acc[zf][1], 0, 0, 0);
    }
  }

  // ---------------- per-channel stats (sum, sumsq) --------------------------
#pragma unroll
  for (int zf = 0; zf < 4; ++zf) {
    float s[4], ss[4];
#pragma unroll
    for (int r = 0; r < 4; ++r) {
      s[r]  = acc[zf][0][r] + acc[zf][1][r];
      ss[r] = acc[zf][0][r] * acc[zf][0][r] + acc[zf][1][r] * acc[zf][1][r];
    }
#pragma unroll
    for (int off = 1; off <= 8; off <<= 1) {
#pragma unroll
      for (int r = 0; r < 4; ++r) {
        s[r]  += __shfl_xor(s[r], off);
        ss[r] += __shfl_xor(ss[r], off);
      }
    }
    if (llo == 0) {
      const int ch = g * 256 + z0 + zf * 16 + lhi * 4;
#pragma unroll
      for (int r = 0; r < 4; ++r) {
        atomicAdd(&stats[2 * (ch + r)],     s[r]);
        atomicAdd(&stats[2 * (ch + r) + 1], ss[r]);
      }
    }
  }

  // ---------------- store raw conv to d_out in fold layout ------------------
#pragma unroll
  for (int zf = 0; zf < 4; ++zf) {
    const int zch = z0 + zf * 16 + lhi * 4;     // + r below
#pragma unroll
    for (int mf = 0; mf < 2; ++mf) {
      const int mm  = w * 32 + mf * 16 + llo;
      const int bb  = mm >> 4;
      const int o_y = (mm >> 2) & 3;
      const int o_x = mm & 3;
      float* op = out + (((size_t)bb * 256 + zch) * 32 + hp * 4 + o_y) * 32
                      + wp * 4 + o_x;
#pragma unroll
      for (int r = 0; r < 4; ++r) op[(size_t)r * 1024] = acc[zf][mf][r];
    }
  }
}

// Pass 2: in-place BatchNorm (batch stats) + LeakyReLU on the fold-layout buffer.
__global__ __launch_bounds__(256) void bn_lrelu(
    float* __restrict__ out,
    const float* __restrict__ stats,
    const float* __restrict__ gamma,
    const float* __restrict__ beta)
{
  size_t t = (size_t)blockIdx.x * blockDim.x + threadIdx.x;
  size_t o = t * 4;                    // float4 per thread
  int X0 = (int)(o & 31);
  int Y  = (int)((o >> 5) & 31);
  int z  = (int)((o >> 10) & 255);
  int ch = ((Y >> 2) * 8 + (X0 >> 2)) * 256 + z;  // (hp*8+wp)*256 + z
  float s  = stats[2 * ch];
  float ss = stats[2 * ch + 1];
  float mean = s * (1.f / 512.f);
  float var  = fmaf(-mean, mean, ss * (1.f / 512.f));
  float inv  = gamma[ch] * rsqrtf(var + kEps);
  float sh   = fmaf(-mean, inv, beta[ch]);
  float4 v = *(float4*)&out[o];
  float vv[4] = {v.x, v.y, v.z, v.w};
#pragma unroll
  for (int j = 0; j < 4; ++j) {
    float y = fmaf(vv[j], inv, sh);
    vv[j] = y > 0.f ? y : kLrelu * y;
  }
  *(float4*)&out[o] = make_float4(vv[0], vv[1], vv[2], vv[3]);
}

extern "C" void kernel_launch(void* const* d_in, const int* in_sizes, int n_in,
                              void* d_out, int out_size, void* d_ws, size_t ws_size,
                              hipStream_t stream) {
  const float* input  = (const float*)d_in[0];
  const float* weight = (const float*)d_in[1];
  const float* gamma  = (const float*)d_in[2];
  const float* beta   = (const float*)d_in[3];
  float* out   = (float*)d_out;
  float* stats = (float*)d_ws;  // 16384 * 2 floats = 128 KB

  (void)hipMemsetAsync(stats, 0, (size_t)16384 * 2 * sizeof(float), stream);

  conv_mfma<<<256, 1024, 0, stream>>>(input, weight, out, stats);

  int n4 = out_size / 4;               // 2,097,152 float4s
  bn_lrelu<<<(n4 + 255) / 256, 256, 0, stream>>>(out, stats, gamma, beta);
}

// Round 4
// 134.040 us; speedup vs baseline: 3.9962x; 3.4160x over previous
//
#include <hip/hip_runtime.h>

namespace {
constexpr float kLrelu = 0.2f;
constexpr float kEps   = 1e-5f;
}

typedef short bf16x8 __attribute__((ext_vector_type(8)));
typedef float f32x4  __attribute__((ext_vector_type(4)));

// round-to-nearest-even f32 -> bf16 (inputs are finite)
static __device__ __forceinline__ unsigned f2bf(float x) {
  unsigned u = __float_as_uint(x);
  return (u + 0x7FFFu + ((u >> 16) & 1u)) >> 16;
}
static __device__ __forceinline__ unsigned packbf(float a, float b) {
  return f2bf(a) | (f2bf(b) << 16);
}

// Grouped conv as 64 x [256x512x2048] bf16-MFMA GEMM + per-channel stats.
// Block = (group g, z-tile of 64, m-tile of 256). 512 threads = 8 waves.
// Per K-chunk (BK=32 = 2 input channels):
//   coalesced float4 raw-patch staging (dbuf, depth-2 prefetch) ->
//   im2col gather from LDS -> bf16 B-tile -> MFMA.
// Writes raw conv output into d_out in FOLD layout: out[b][z][hp*4+oy][wp*4+ox].
__global__ __launch_bounds__(512, 4) void conv_mfma(
    const float* __restrict__ input,   // [32,128,64,64]
    const float* __restrict__ weight,  // [16384, 2048]  (k = nc*16 + ky*4 + kx)
    float* __restrict__ out,           // [32,256,32,32]
    float* __restrict__ stats)         // [16384][2] (sum, sumsq)
{
  // raw patch tiles: 32 patches (16 b x 2 nc) x 64 floats, row-XOR-swizzled:
  //   float addr = pl*64 + ((py ^ (bl&7))<<3) + px
  __shared__ __align__(16) float raw0[32 * 64];   // 8 KB
  __shared__ __align__(16) float raw1[32 * 64];   // 8 KB
  // GEMM tiles, row = 64B (32 bf16 = BK), 16B-granule XOR swizzle (g' ^ ((r>>1)&3))
  __shared__ __align__(16) char Bs[256 * 64];     // 16 KB
  __shared__ __align__(16) char As[64 * 64];      // 4 KB

  const int bid  = blockIdx.x;
  const int orig = (bid & 7) * 64 + (bid >> 3);   // XCD-chunked (512 % 8 == 0)
  const int g    = orig >> 3;                     // group: 8 per XCD
  const int zt   = (orig >> 1) & 3;
  const int mt   = orig & 1;
  const int hp = g >> 3, wp = g & 7;
  const int z0 = zt * 64;
  const int m0 = mt * 256;

  const int tid  = threadIdx.x;
  const int lane = tid & 63;
  const int w    = tid >> 6;                      // wave 0..7, m-range = m0 + w*32
  const int llo  = lane & 15, lhi = lane >> 4;

  // ---------------- raw loader mapping: one float4 / thread / chunk ---------
  const int pl_w  = tid >> 4;                     // patch 0..31
  const int qq    = tid & 15;
  const int py_w  = qq >> 1, h_w = qq & 1;
  const int bl_w  = pl_w >> 1;
  const int ncs_w = pl_w & 1;
  const float* const gsrc = input
      + ((size_t)(mt * 16 + bl_w) * 128 + ncs_w) * 4096
      + (hp * 8 + py_w) * 64 + wp * 8 + (h_w << 2);     // + ck*2*4096 per chunk
  const int roff = pl_w * 64 + ((py_w ^ (bl_w & 7)) << 3) + (h_w << 2);
  float* const rdst0 = raw0 + roff;
  float* const rdst1 = raw1 + roff;

  // ---------------- gather mapping (thread -> (m-local, ncs)) ---------------
  const int ml  = tid & 255;                      // m local
  const int ncs = tid >> 8;
  const int bl  = ml >> 4;                        // b local 0..15
  const int oy  = (ml >> 2) & 3;
  const int ox  = ml & 3;
  const int plg = bl * 2 + ncs;
  const int swz = bl & 7;

  int      goff[16];                              // float offsets into raw buf
  unsigned bmask[8];
  {
    unsigned short vm[16];
#pragma unroll
    for (int ky = 0; ky < 4; ++ky) {
#pragma unroll
      for (int kx = 0; kx < 4; ++kx) {
        const int t  = ky * 4 + kx;
        const int iy = 2 * oy - 1 + ky;
        const int ix = 2 * ox - 1 + kx;
        const bool ok = ((unsigned)iy < 8u) && ((unsigned)ix < 8u);
        const int iyc = iy < 0 ? 0 : (iy > 7 ? 7 : iy);
        const int ixc = ix < 0 ? 0 : (ix > 7 ? 7 : ix);
        goff[t] = plg * 64 + ((iyc ^ swz) << 3) + ixc;
        vm[t] = ok ? (unsigned short)0xFFFFu : (unsigned short)0;
      }
    }
#pragma unroll
    for (int j = 0; j < 8; ++j)
      bmask[j] = (unsigned)vm[2 * j] | ((unsigned)vm[2 * j + 1] << 16);
  }
  const int swzB = (ml >> 1) & 3;
  char* const bw0 = Bs + ml * 64 + (((2 * ncs)     ^ swzB) << 4);
  char* const bw1 = Bs + ml * 64 + (((2 * ncs + 1) ^ swzB) << 4);

  // ---------------- A (weights): one float4 / thread / chunk ----------------
  const int az = tid >> 3;                        // z row 0..63
  const int s4 = tid & 7;                         // k quad: k = s4*4..s4*4+3
  const float* const wrow =
      weight + ((size_t)(g * 256 + z0 + az)) * 2048 + s4 * 4;
  char* const asp = As + az * 64
      + (((s4 >> 1) ^ ((az >> 1) & 3)) << 4) + ((s4 & 1) << 3);

  // ---------------- fragment read pointers ----------------------------------
  const char* afp[4];
#pragma unroll
  for (int zf = 0; zf < 4; ++zf) {
    const int ar = zf * 16 + llo;
    afp[zf] = As + ar * 64 + ((lhi ^ ((ar >> 1) & 3)) << 4);
  }
  const char* bfp[2];
#pragma unroll
  for (int mf = 0; mf < 2; ++mf) {
    const int mr = w * 32 + mf * 16 + llo;        // local row in Bs
    bfp[mf] = Bs + mr * 64 + ((lhi ^ ((mr >> 1) & 3)) << 4);
  }

  f32x4 acc[4][2] = {};

  // ---------------- prologue: prefetch chunks 0,1; stage chunk 0 ------------
  float4 rA = *(const float4*)(gsrc);             // chunk 0
  float4 rB = *(const float4*)(gsrc + 2 * 4096);  // chunk 1
  float4 wA = *(const float4*)(wrow);             // chunk 0 weights
  float4 wB = *(const float4*)(wrow + 32);        // chunk 1 weights
  *(float4*)rdst0 = rA;
  __syncthreads();

  for (int ck = 0; ck < 64; ck += 2) {
    // ================= even chunk ck (raw0) =================
    {
      float fv[16];
#pragma unroll
      for (int t = 0; t < 16; ++t) fv[t] = raw0[goff[t]];
      unsigned u[8];
#pragma unroll
      for (int j = 0; j < 8; ++j) u[j] = packbf(fv[2 * j], fv[2 * j + 1]) & bmask[j];
      const unsigned a0 = packbf(wA.x, wA.y);
      const unsigned a1 = packbf(wA.z, wA.w);
      if (ck + 2 < 64) {
        rA = *(const float4*)(gsrc + (size_t)(ck + 2) * 2 * 4096);
        wA = *(const float4*)(wrow + (ck + 2) * 32);
      }
      __syncthreads();   // previous MFMAs done reading tiles
      *(uint2*)asp = make_uint2(a0, a1);
      uint4 q0; q0.x = u[0]; q0.y = u[1]; q0.z = u[2]; q0.w = u[3];
      uint4 q1; q1.x = u[4]; q1.y = u[5]; q1.z = u[6]; q1.w = u[7];
      *(uint4*)bw0 = q0;
      *(uint4*)bw1 = q1;
      *(float4*)rdst1 = rB;                       // stage chunk ck+1
      __syncthreads();   // tiles + raw1 visible
      const bf16x8 bf0 = *(const bf16x8*)bfp[0];
      const bf16x8 bf1 = *(const bf16x8*)bfp[1];
#pragma unroll
      for (int zf = 0; zf < 4; ++zf) {
        const bf16x8 af = *(const bf16x8*)afp[zf];
        acc[zf][0] = __builtin_amdgcn_mfma_f32_16x16x32_bf16(af, bf0, acc[zf][0], 0, 0, 0);
        acc[zf][1] = __builtin_amdgcn_mfma_f32_16x16x32_bf16(af, bf1, acc[zf][1], 0, 0, 0);
      }
    }
    // ================= odd chunk ck+1 (raw1) =================
    {
      float fv[16];
#pragma unroll
      for (int t = 0; t < 16; ++t) fv[t] = raw1[goff[t]];
      unsigned u[8];
#pragma unroll
      for (int j = 0; j < 8; ++j) u[j] = packbf(fv[2 * j], fv[2 * j + 1]) & bmask[j];
      const unsigned a0 = packbf(wB.x, wB.y);
      const unsigned a1 = packbf(wB.z, wB.w);
      if (ck + 3 < 64) {
        rB = *(const float4*)(gsrc + (size_t)(ck + 3) * 2 * 4096);
        wB = *(const float4*)(wrow + (ck + 3) * 32);
      }
      __syncthreads();
      *(uint2*)asp = make_uint2(a0, a1);
      uint4 q0; q0.x = u[0]; q0.y = u[1]; q0.z = u[2]; q0.w = u[3];
      uint4 q1; q1.x = u[4]; q1.y = u[5]; q1.z = u[6]; q1.w = u[7];
      *(uint4*)bw0 = q0;
      *(uint4*)bw1 = q1;
      if (ck + 2 < 64) *(float4*)rdst0 = rA;      // stage chunk ck+2
      __syncthreads();
      const bf16x8 bf0 = *(const bf16x8*)bfp[0];
      const bf16x8 bf1 = *(const bf16x8*)bfp[1];
#pragma unroll
      for (int zf = 0; zf < 4; ++zf) {
        const bf16x8 af = *(const bf16x8*)afp[zf];
        acc[zf][0] = __builtin_amdgcn_mfma_f32_16x16x32_bf16(af, bf0, acc[zf][0], 0, 0, 0);
        acc[zf][1] = __builtin_amdgcn_mfma_f32_16x16x32_bf16(af, bf1, acc[zf][1], 0, 0, 0);
      }
    }
  }

  // ---------------- per-channel stats (sum, sumsq) --------------------------
#pragma unroll
  for (int zf = 0; zf < 4; ++zf) {
    float s[4], ss[4];
#pragma unroll
    for (int r = 0; r < 4; ++r) {
      s[r]  = acc[zf][0][r] + acc[zf][1][r];
      ss[r] = acc[zf][0][r] * acc[zf][0][r] + acc[zf][1][r] * acc[zf][1][r];
    }
#pragma unroll
    for (int off = 1; off <= 8; off <<= 1) {
#pragma unroll
      for (int r = 0; r < 4; ++r) {
        s[r]  += __shfl_xor(s[r], off);
        ss[r] += __shfl_xor(ss[r], off);
      }
    }
    if (llo == 0) {
      const int ch = g * 256 + z0 + zf * 16 + lhi * 4;
#pragma unroll
      for (int r = 0; r < 4; ++r) {
        atomicAdd(&stats[2 * (ch + r)],     s[r]);
        atomicAdd(&stats[2 * (ch + r) + 1], ss[r]);
      }
    }
  }

  // ---------------- store raw conv to d_out in fold layout ------------------
#pragma unroll
  for (int zf = 0; zf < 4; ++zf) {
    const int zch = z0 + zf * 16 + lhi * 4;       // + r below
#pragma unroll
    for (int mf = 0; mf < 2; ++mf) {
      const int mm  = m0 + w * 32 + mf * 16 + llo;
      const int bb  = mm >> 4;
      const int o_y = (mm >> 2) & 3;
      const int o_x = mm & 3;
      float* op = out + (((size_t)bb * 256 + zch) * 32 + hp * 4 + o_y) * 32
                      + wp * 4 + o_x;
#pragma unroll
      for (int r = 0; r < 4; ++r) op[(size_t)r * 1024] = acc[zf][mf][r];
    }
  }
}

// Pass 2: in-place BatchNorm (batch stats) + LeakyReLU on the fold-layout buffer.
__global__ __launch_bounds__(256) void bn_lrelu(
    float* __restrict__ out,
    const float* __restrict__ stats,
    const float* __restrict__ gamma,
    const float* __restrict__ beta)
{
  size_t t = (size_t)blockIdx.x * blockDim.x + threadIdx.x;
  size_t o = t * 4;                    // float4 per thread
  int X0 = (int)(o & 31);
  int Y  = (int)((o >> 5) & 31);
  int z  = (int)((o >> 10) & 255);
  int ch = ((Y >> 2) * 8 + (X0 >> 2)) * 256 + z;  // (hp*8+wp)*256 + z
  float s  = stats[2 * ch];
  float ss = stats[2 * ch + 1];
  float mean = s * (1.f / 512.f);
  float var  = fmaf(-mean, mean, ss * (1.f / 512.f));
  float inv  = gamma[ch] * rsqrtf(var + kEps);
  float sh   = fmaf(-mean, inv, beta[ch]);
  float4 v = *(float4*)&out[o];
  float vv[4] = {v.x, v.y, v.z, v.w};
#pragma unroll
  for (int j = 0; j < 4; ++j) {
    float y = fmaf(vv[j], inv, sh);
    vv[j] = y > 0.f ? y : kLrelu * y;
  }
  *(float4*)&out[o] = make_float4(vv[0], vv[1], vv[2], vv[3]);
}

extern "C" void kernel_launch(void* const* d_in, const int* in_sizes, int n_in,
                              void* d_out, int out_size, void* d_ws, size_t ws_size,
                              hipStream_t stream) {
  const float* input  = (const float*)d_in[0];
  const float* weight = (const float*)d_in[1];
  const float* gamma  = (const float*)d_in[2];
  const float* beta   = (const float*)d_in[3];
  float* out   = (float*)d_out;
  float* stats = (float*)d_ws;  // 16384 * 2 floats = 128 KB

  (void)hipMemsetAsync(stats, 0, (size_t)16384 * 2 * sizeof(float), stream);

  conv_mfma<<<512, 512, 0, stream>>>(input, weight, out, stats);

  int n4 = out_size / 4;               // 2,097,152 float4s
  bn_lrelu<<<(n4 + 255) / 256, 256, 0, stream>>>(out, stats, gamma, beta);
}

// Round 5
// 112.946 us; speedup vs baseline: 4.7425x; 1.1868x over previous
//
#include <hip/hip_runtime.h>

namespace {
constexpr float kLrelu = 0.2f;
constexpr float kEps   = 1e-5f;
}

typedef short bf16x8 __attribute__((ext_vector_type(8)));
typedef float f32x4  __attribute__((ext_vector_type(4)));

// round-to-nearest-even f32 -> bf16 (inputs are finite)
static __device__ __forceinline__ unsigned f2bf(float x) {
  unsigned u = __float_as_uint(x);
  return (u + 0x7FFFu + ((u >> 16) & 1u)) >> 16;
}
static __device__ __forceinline__ unsigned packbf(float a, float b) {
  return f2bf(a) | (f2bf(b) << 16);
}

// Grouped conv as 64 x [256x512x2048] bf16-MFMA GEMM + per-channel stats.
// Block = (g, z-tile 64, m-tile 256), 256 threads = 4 waves, wave tile 64z x 64m.
// Per K-chunk (BK=32 = 2 input channels): coalesced raw-patch staging (dbuf,
// depth-2 reg prefetch) -> ROW-gather (2x ds_read_b128 per row, compile-time
// tap selects) -> bf16 B-tile -> 16 MFMA per wave.
// Writes raw conv output into d_out in FOLD layout: out[b][z][hp*4+oy][wp*4+ox].
__global__ __launch_bounds__(256, 2) void conv_mfma(
    const float* __restrict__ input,   // [32,128,64,64]
    const float* __restrict__ weight,  // [16384, 2048]  (k = nc*16 + ky*4 + kx)
    float* __restrict__ out,           // [32,256,32,32]
    float* __restrict__ stats)         // [16384][2] (sum, sumsq)
{
  // raw patch tiles: 32 patches (16 b x 2 nc) x 64 floats, row-XOR swizzle:
  //   addr(fl) = pl*64 + ((py ^ (bl&7))<<3) + px
  __shared__ __align__(16) float raw0[32 * 64];   // 8 KB
  __shared__ __align__(16) float raw1[32 * 64];   // 8 KB
  // GEMM tiles, row = 64B (32 bf16), 16B-granule XOR swizzle (gk ^ ((row>>1)&3))
  __shared__ __align__(16) char Bs[256 * 64];     // 16 KB
  __shared__ __align__(16) char As[64 * 64];      // 4 KB

  const int bid  = blockIdx.x;
  const int orig = (bid & 7) * 64 + (bid >> 3);   // XCD-chunked (512 % 8 == 0)
  const int g    = orig >> 3;
  const int zt   = (orig >> 1) & 3;
  const int mt   = orig & 1;
  const int hp = g >> 3, wp = g & 7;
  const int z0 = zt * 64;
  const int m0 = mt * 256;

  const int tid  = threadIdx.x;
  const int lane = tid & 63;
  const int w    = tid >> 6;                      // wave 0..3, m-range = m0 + w*64
  const int llo  = lane & 15, lhi = lane >> 4;

  // -------- raw staging: thread -> patch pl=tid>>3, f4=tid&7 (rows 0-3 / 4-7)
  const int pl_s = tid >> 3;
  const int f4   = tid & 7;
  const int bl_s = pl_s >> 1;
  const int ncs_s = pl_s & 1;
  const int py_s = f4 >> 1, h_s = f4 & 1;
  const float* const gsrc = input
      + ((size_t)(mt * 16 + bl_s) * 128 + ncs_s) * 4096
      + (hp * 8 + py_s) * 64 + wp * 8 + (h_s << 2);   // 2nd load: +256 floats (py+4)
  const int roffA = pl_s * 64 + ((py_s ^ (bl_s & 7)) << 3) + (h_s << 2);
  const int roffB = pl_s * 64 + (((py_s + 4) ^ (bl_s & 7)) << 3) + (h_s << 2);
  float* const rd0a = raw0 + roffA;  float* const rd0b = raw0 + roffB;
  float* const rd1a = raw1 + roffA;  float* const rd1b = raw1 + roffB;

  // -------- weight staging: rows az0=tid>>3 and az0+32; kq=tid&7 (k=kq*4..+3)
  const int az0 = tid >> 3;
  const int kq  = tid & 7;
  const float* const wsrc =
      weight + ((size_t)(g * 256 + z0 + az0)) * 2048 + kq * 4;  // 2nd: +65536
  const int aswz = (az0 >> 1) & 3;   // ((az0+32)>>1)&3 is identical
  char* const ad0 = As + az0 * 64 + (((kq >> 1) ^ aswz) << 4) + ((kq & 1) << 3);
  char* const ad1 = ad0 + 32 * 64;

  // -------- row-gather: thread -> (bl=tid>>4, oy=(tid>>2)&3, ky=tid&3)
  const int bl_g = tid >> 4;
  const int oy_g = (tid >> 2) & 3;
  const int ky_g = tid & 3;
  const int iy   = 2 * oy_g - 1 + ky_g;
  const unsigned rowm = ((unsigned)iy < 8u) ? 0xFFFFFFFFu : 0u;
  const int iyc  = iy < 0 ? 0 : (iy > 7 ? 7 : iy);
  const int swzg = bl_g & 7;
  const int gro0 = (bl_g * 2 + 0) * 64 + ((iyc ^ swzg) << 3);
  const int gro1 = (bl_g * 2 + 1) * 64 + ((iyc ^ swzg) << 3);
  // B-write dsts: ml = bl*16+oy*4+ox, byte col = ncs*32 + ky*8
  char* bwd[2][4];
#pragma unroll
  for (int ncs = 0; ncs < 2; ++ncs)
#pragma unroll
    for (int ox = 0; ox < 4; ++ox) {
      const int ml = bl_g * 16 + oy_g * 4 + ox;
      const int gk = ncs * 2 + (ky_g >> 1);
      bwd[ncs][ox] = Bs + ml * 64 + ((gk ^ ((ml >> 1) & 3)) << 4) + ((ky_g & 1) << 3);
    }

  // -------- fragment read pointers
  const char* afp[4];
#pragma unroll
  for (int zf = 0; zf < 4; ++zf) {
    const int ar = zf * 16 + llo;
    afp[zf] = As + ar * 64 + ((lhi ^ ((ar >> 1) & 3)) << 4);
  }
  const char* bfp[4];
#pragma unroll
  for (int mf = 0; mf < 4; ++mf) {
    const int mr = w * 64 + mf * 16 + llo;
    bfp[mf] = Bs + mr * 64 + ((lhi ^ ((mr >> 1) & 3)) << 4);
  }

  f32x4 acc[4][4] = {};

  // tap selects: row[0..7] = r0.xyzw r1.xyzw; tap(ox,kx) = row[2ox-1+kx]
  uint2 ub[2][4];
  auto gather = [&](const float* rw) {
#pragma unroll
    for (int ncs = 0; ncs < 2; ++ncs) {
      const int gro = ncs ? gro1 : gro0;
      const float4 r0 = *(const float4*)(rw + gro);
      const float4 r1 = *(const float4*)(rw + gro + 4);
      uint2 t;
      t.x = packbf(0.f, r0.x) & rowm;  t.y = packbf(r0.y, r0.z) & rowm;  ub[ncs][0] = t;
      t.x = packbf(r0.y, r0.z) & rowm; t.y = packbf(r0.w, r1.x) & rowm;  ub[ncs][1] = t;
      t.x = packbf(r0.w, r1.x) & rowm; t.y = packbf(r1.y, r1.z) & rowm;  ub[ncs][2] = t;
      t.x = packbf(r1.y, r1.z) & rowm; t.y = packbf(r1.w, 0.f) & rowm;   ub[ncs][3] = t;
    }
  };
  auto writeB = [&]() {
#pragma unroll
    for (int ncs = 0; ncs < 2; ++ncs)
#pragma unroll
      for (int ox = 0; ox < 4; ++ox) *(uint2*)bwd[ncs][ox] = ub[ncs][ox];
  };
  auto domfma = [&]() {
    bf16x8 bfv[4];
#pragma unroll
    for (int mf = 0; mf < 4; ++mf) bfv[mf] = *(const bf16x8*)bfp[mf];
#pragma unroll
    for (int zf = 0; zf < 4; ++zf) {
      const bf16x8 af = *(const bf16x8*)afp[zf];
#pragma unroll
      for (int mf = 0; mf < 4; ++mf)
        acc[zf][mf] = __builtin_amdgcn_mfma_f32_16x16x32_bf16(af, bfv[mf], acc[zf][mf], 0, 0, 0);
    }
  };

  // -------- prologue: prefetch chunks 0,1; stage chunk 0 into raw0
  float4 ra0 = *(const float4*)(gsrc);
  float4 ra1 = *(const float4*)(gsrc + 256);
  float4 rb0 = *(const float4*)(gsrc + 8192);
  float4 rb1 = *(const float4*)(gsrc + 8192 + 256);
  float4 wa0 = *(const float4*)(wsrc);
  float4 wa1 = *(const float4*)(wsrc + 65536);
  float4 wb0 = *(const float4*)(wsrc + 32);
  float4 wb1 = *(const float4*)(wsrc + 65536 + 32);
  *(float4*)rd0a = ra0;
  *(float4*)rd0b = ra1;
  __syncthreads();

  for (int ck = 0; ck < 64; ck += 2) {
    // ============ even chunk ck (gather raw0, stage ck+1 -> raw1) ============
    {
      gather(raw0);
      uint2 a0w, a1w;
      a0w.x = packbf(wa0.x, wa0.y); a0w.y = packbf(wa0.z, wa0.w);
      a1w.x = packbf(wa1.x, wa1.y); a1w.y = packbf(wa1.z, wa1.w);
      if (ck + 2 < 64) {
        ra0 = *(const float4*)(gsrc + (size_t)(ck + 2) * 8192);
        ra1 = *(const float4*)(gsrc + (size_t)(ck + 2) * 8192 + 256);
        wa0 = *(const float4*)(wsrc + (ck + 2) * 32);
        wa1 = *(const float4*)(wsrc + 65536 + (ck + 2) * 32);
      }
      __syncthreads();             // prev MFMAs + this gather done reading LDS
      *(uint2*)ad0 = a0w;
      *(uint2*)ad1 = a1w;
      writeB();
      *(float4*)rd1a = rb0;        // stage chunk ck+1
      *(float4*)rd1b = rb1;
      __syncthreads();
      domfma();
    }
    // ============ odd chunk ck+1 (gather raw1, stage ck+2 -> raw0) ===========
    {
      gather(raw1);
      uint2 a0w, a1w;
      a0w.x = packbf(wb0.x, wb0.y); a0w.y = packbf(wb0.z, wb0.w);
      a1w.x = packbf(wb1.x, wb1.y); a1w.y = packbf(wb1.z, wb1.w);
      if (ck + 3 < 64) {
        rb0 = *(const float4*)(gsrc + (size_t)(ck + 3) * 8192);
        rb1 = *(const float4*)(gsrc + (size_t)(ck + 3) * 8192 + 256);
        wb0 = *(const float4*)(wsrc + (ck + 3) * 32);
        wb1 = *(const float4*)(wsrc + 65536 + (ck + 3) * 32);
      }
      __syncthreads();
      *(uint2*)ad0 = a0w;
      *(uint2*)ad1 = a1w;
      writeB();
      if (ck + 2 < 64) { *(float4*)rd0a = ra0; *(float4*)rd0b = ra1; }
      __syncthreads();
      domfma();
    }
  }

  // -------- per-channel stats (sum, sumsq) over the wave's 64 m
#pragma unroll
  for (int zf = 0; zf < 4; ++zf) {
    float s[4], ss[4];
#pragma unroll
    for (int r = 0; r < 4; ++r) {
      s[r]  = acc[zf][0][r] + acc[zf][1][r] + acc[zf][2][r] + acc[zf][3][r];
      ss[r] = acc[zf][0][r] * acc[zf][0][r] + acc[zf][1][r] * acc[zf][1][r]
            + acc[zf][2][r] * acc[zf][2][r] + acc[zf][3][r] * acc[zf][3][r];
    }
#pragma unroll
    for (int off = 1; off <= 8; off <<= 1) {
#pragma unroll
      for (int r = 0; r < 4; ++r) {
        s[r]  += __shfl_xor(s[r], off);
        ss[r] += __shfl_xor(ss[r], off);
      }
    }
    if (llo == 0) {
      const int ch = g * 256 + z0 + zf * 16 + lhi * 4;
#pragma unroll
      for (int r = 0; r < 4; ++r) {
        atomicAdd(&stats[2 * (ch + r)],     s[r]);
        atomicAdd(&stats[2 * (ch + r) + 1], ss[r]);
      }
    }
  }

  // -------- store raw conv to d_out in fold layout
#pragma unroll
  for (int zf = 0; zf < 4; ++zf) {
    const int zch = z0 + zf * 16 + lhi * 4;       // + r below
#pragma unroll
    for (int mf = 0; mf < 4; ++mf) {
      const int mm  = m0 + w * 64 + mf * 16 + llo;
      const int bb  = mm >> 4;
      const int o_y = (mm >> 2) & 3;
      const int o_x = mm & 3;
      float* op = out + (((size_t)bb * 256 + zch) * 32 + hp * 4 + o_y) * 32
                      + wp * 4 + o_x;
#pragma unroll
      for (int r = 0; r < 4; ++r) op[(size_t)r * 1024] = acc[zf][mf][r];
    }
  }
}

// Pass 2: in-place BatchNorm (batch stats) + LeakyReLU on the fold-layout buffer.
__global__ __launch_bounds__(256) void bn_lrelu(
    float* __restrict__ out,
    const float* __restrict__ stats,
    const float* __restrict__ gamma,
    const float* __restrict__ beta)
{
  size_t t = (size_t)blockIdx.x * blockDim.x + threadIdx.x;
  size_t o = t * 4;                    // float4 per thread
  int X0 = (int)(o & 31);
  int Y  = (int)((o >> 5) & 31);
  int z  = (int)((o >> 10) & 255);
  int ch = ((Y >> 2) * 8 + (X0 >> 2)) * 256 + z;  // (hp*8+wp)*256 + z
  float s  = stats[2 * ch];
  float ss = stats[2 * ch + 1];
  float mean = s * (1.f / 512.f);
  float var  = fmaf(-mean, mean, ss * (1.f / 512.f));
  float inv  = gamma[ch] * rsqrtf(var + kEps);
  float sh   = fmaf(-mean, inv, beta[ch]);
  float4 v = *(float4*)&out[o];
  float vv[4] = {v.x, v.y, v.z, v.w};
#pragma unroll
  for (int j = 0; j < 4; ++j) {
    float y = fmaf(vv[j], inv, sh);
    vv[j] = y > 0.f ? y : kLrelu * y;
  }
  *(float4*)&out[o] = make_float4(vv[0], vv[1], vv[2], vv[3]);
}

extern "C" void kernel_launch(void* const* d_in, const int* in_sizes, int n_in,
                              void* d_out, int out_size, void* d_ws, size_t ws_size,
                              hipStream_t stream) {
  const float* input  = (const float*)d_in[0];
  const float* weight = (const float*)d_in[1];
  const float* gamma  = (const float*)d_in[2];
  const float* beta   = (const float*)d_in[3];
  float* out   = (float*)d_out;
  float* stats = (float*)d_ws;  // 16384 * 2 floats = 128 KB

  (void)hipMemsetAsync(stats, 0, (size_t)16384 * 2 * sizeof(float), stream);

  conv_mfma<<<512, 256, 0, stream>>>(input, weight, out, stats);

  int n4 = out_size / 4;               // 2,097,152 float4s
  bn_lrelu<<<(n4 + 255) / 256, 256, 0, stream>>>(out, stats, gamma, beta);
}